// Round 1
// baseline (1438.812 us; speedup 1.0000x reference)
//
#include <hip/hip_runtime.h>
#include <math.h>

#define LDIM 2048
#define DDIM 128
#define BDIM 16
#define FDIM 100
#define TCONV 16

__device__ inline void ins3(float w, int idx, float v[3], int id[3]) {
  if (w > v[2]) {
    if (w > v[0]) { v[2]=v[1]; id[2]=id[1]; v[1]=v[0]; id[1]=id[0]; v[0]=w; id[0]=idx; }
    else if (w > v[1]) { v[2]=v[1]; id[2]=id[1]; v[1]=w; id[1]=idx; }
    else { v[2]=w; id[2]=idx; }
  }
}

// W[b][c][m] = dot(ctx[b][c][:], main[b][m][:]); 64x64 tile, K=128 in two 64-phases.
__global__ __launch_bounds__(256) void gemm_nt(const float* __restrict__ ctx,
                                               const float* __restrict__ mn,
                                               float* __restrict__ W) {
  __shared__ float As[64][68];   // pad 68: float4-aligned rows, reads <=2-way conflict
  __shared__ float Bs[64][68];
  const int b = blockIdx.z;
  const int c0 = blockIdx.y * 64;
  const int m0 = blockIdx.x * 64;
  const float4* A4 = (const float4*)(ctx + ((size_t)b*LDIM + c0)*DDIM);
  const float4* B4 = (const float4*)(mn  + ((size_t)b*LDIM + m0)*DDIM);
  const int tid = threadIdx.x;
  const int tx = tid & 15, ty = tid >> 4;
  float acc[4][4] = {};
  for (int kt = 0; kt < DDIM; kt += 64) {
    const int kq = kt >> 2;
    __syncthreads();
    for (int e = tid; e < 64*16; e += 256) {
      int r = e >> 4, q = e & 15;
      *(float4*)&As[r][q*4] = A4[(size_t)r*32 + kq + q];
      *(float4*)&Bs[r][q*4] = B4[(size_t)r*32 + kq + q];
    }
    __syncthreads();
    #pragma unroll
    for (int k = 0; k < 64; k += 4) {
      float4 a[4], bb[4];
      #pragma unroll
      for (int i = 0; i < 4; i++) a[i] = *(const float4*)&As[ty + 16*i][k];
      #pragma unroll
      for (int j = 0; j < 4; j++) bb[j] = *(const float4*)&Bs[tx + 16*j][k];
      #pragma unroll
      for (int i = 0; i < 4; i++)
        #pragma unroll
        for (int j = 0; j < 4; j++)
          acc[i][j] += a[i].x*bb[j].x + a[i].y*bb[j].y + a[i].z*bb[j].z + a[i].w*bb[j].w;
    }
  }
  float* Wb = W + (size_t)b*LDIM*LDIM;
  #pragma unroll
  for (int i = 0; i < 4; i++) {
    int c = c0 + ty + 16*i;
    #pragma unroll
    for (int j = 0; j < 4; j++)
      Wb[(size_t)c*LDIM + m0 + tx + 16*j] = acc[i][j];
  }
}

// Per row r: top-3 (val,idx) over m, sum, sumsq -> normalized top-3 weights + std.
__global__ __launch_bounds__(256) void row_stats(const float* __restrict__ W,
    float* __restrict__ rw, int* __restrict__ ri, float* __restrict__ rs) {
  const int b = blockIdx.y, r = blockIdx.x, tid = threadIdx.x;
  const float* row = W + ((size_t)b*LDIM + r)*LDIM;
  float v[3] = {-3e38f,-3e38f,-3e38f}; int id[3] = {-1,-1,-1};
  float sum = 0.f, sq = 0.f;
  for (int m = tid; m < LDIM; m += 256) {
    float w = row[m];
    sum += w; sq += w*w;
    ins3(w, m, v, id);
  }
  __shared__ float shv[128][3];
  __shared__ int   shi[128][3];
  __shared__ float shs[128], shq[128];
  for (int s = 128; s > 0; s >>= 1) {
    if (tid >= s && tid < 2*s) {
      int o = tid - s;
      shv[o][0]=v[0]; shv[o][1]=v[1]; shv[o][2]=v[2];
      shi[o][0]=id[0]; shi[o][1]=id[1]; shi[o][2]=id[2];
      shs[o]=sum; shq[o]=sq;
    }
    __syncthreads();
    if (tid < s) {
      #pragma unroll
      for (int t = 0; t < 3; t++) ins3(shv[tid][t], shi[tid][t], v, id);
      sum += shs[tid]; sq += shq[tid];
    }
    __syncthreads();
  }
  if (tid == 0) {
    float inv = 1.f/(v[0]+v[1]+v[2]);
    size_t base = (size_t)b*LDIM + r;
    rw[base*3+0]=v[0]*inv; rw[base*3+1]=v[1]*inv; rw[base*3+2]=v[2]*inv;
    ri[base*3+0]=id[0]; ri[base*3+1]=id[1]; ri[base*3+2]=id[2];
    float mean = sum * (1.f/LDIM);
    float var = sq*(1.f/LDIM) - mean*mean;
    rs[base] = sqrtf(fmaxf(var, 0.f));
  }
}

// Per col m (tile of 64 cols/block, coalesced): top-3 over c, sum, sumsq.
__global__ __launch_bounds__(256) void col_stats(const float* __restrict__ W,
    float* __restrict__ cw, int* __restrict__ ci, float* __restrict__ cs) {
  const int b = blockIdx.y;
  const int m0 = blockIdx.x * 64;
  const int tid = threadIdx.x;
  const int tx = tid & 63, ty = tid >> 6;   // 64 cols x 4 row-groups
  const float* Wb = W + (size_t)b*LDIM*LDIM;
  float v[3] = {-3e38f,-3e38f,-3e38f}; int id[3] = {-1,-1,-1};
  float sum = 0.f, sq = 0.f;
  for (int c = ty; c < LDIM; c += 4) {
    float w = Wb[(size_t)c*LDIM + m0 + tx];
    sum += w; sq += w*w;
    ins3(w, c, v, id);
  }
  __shared__ float shv[128][3];
  __shared__ int   shi[128][3];
  __shared__ float shs[128], shq[128];
  for (int s = 2; s > 0; s >>= 1) {
    if (ty >= s && ty < 2*s) {
      int o = (ty - s)*64 + tx;
      shv[o][0]=v[0]; shv[o][1]=v[1]; shv[o][2]=v[2];
      shi[o][0]=id[0]; shi[o][1]=id[1]; shi[o][2]=id[2];
      shs[o]=sum; shq[o]=sq;
    }
    __syncthreads();
    if (ty < s) {
      int o = ty*64 + tx;
      #pragma unroll
      for (int t = 0; t < 3; t++) ins3(shv[o][t], shi[o][t], v, id);
      sum += shs[o]; sq += shq[o];
    }
    __syncthreads();
  }
  if (ty == 0) {
    float inv = 1.f/(v[0]+v[1]+v[2]);
    size_t base = (size_t)b*LDIM + m0 + tx;
    cw[base*3+0]=v[0]*inv; cw[base*3+1]=v[1]*inv; cw[base*3+2]=v[2]*inv;
    ci[base*3+0]=id[0]; ci[base*3+1]=id[1]; ci[base*3+2]=id[2];
    float mean = sum * (1.f/LDIM);
    float var = sq*(1.f/LDIM) - mean*mean;
    cs[base] = sqrtf(fmaxf(var, 0.f));
  }
}

// att_merge_c[m][d] += wk_c[c][m] * ctx[c][d]  -- 3 targets per row c (scatter).
__global__ __launch_bounds__(128) void scatter_att(const float* __restrict__ ctx,
    const float* __restrict__ rw, const int* __restrict__ ri,
    float* __restrict__ attC) {
  const int b = blockIdx.y, c = blockIdx.x, d = threadIdx.x;
  const size_t base = (size_t)b*LDIM + c;
  const float x = ctx[base*DDIM + d];
  #pragma unroll
  for (int t = 0; t < 3; t++) {
    float w = rw[base*3 + t];
    int m = ri[base*3 + t];
    atomicAdd(&attC[((size_t)b*LDIM + m)*DDIM + d], w*x);
  }
}

// outputs_c = |ctx - gather(col top-3 of main)| * row_std
// outputs_m = |main - attC| * col_std
__global__ __launch_bounds__(128) void make_outputs(const float* __restrict__ ctx,
    const float* __restrict__ mn, const float* __restrict__ attC,
    const float* __restrict__ rs, const float* __restrict__ cw,
    const int* __restrict__ ci, const float* __restrict__ cs,
    float* __restrict__ outC, float* __restrict__ outM) {
  const int b = blockIdx.y, i = blockIdx.x, d = threadIdx.x;
  const size_t base = (size_t)b*LDIM + i;
  float am = 0.f;
  #pragma unroll
  for (int t = 0; t < 3; t++)
    am += cw[base*3+t] * mn[((size_t)b*LDIM + ci[base*3+t])*DDIM + d];
  outC[base*DDIM + d] = fabsf(ctx[base*DDIM + d] - am) * rs[base];
  outM[base*DDIM + d] = fabsf(mn[base*DDIM + d] - attC[base*DDIM + d]) * cs[base];
}

// conv1d(KS=3, valid) + bias + relu + maxpool over positions. z=0: outC->pool_c, z=1: outM->pool_m.
__global__ __launch_bounds__(128) void conv_pool(const float* __restrict__ XC,
    const float* __restrict__ XM, const float* __restrict__ wv,
    const float* __restrict__ bias, float* __restrict__ out) {
  const int b = blockIdx.y, z = blockIdx.z;
  const int t0 = blockIdx.x * TCONV;
  const float* X = (z == 0 ? XC : XM) + (size_t)b*LDIM*DDIM;
  __shared__ float Xs[TCONV+2][DDIM];
  const int tid = threadIdx.x;
  for (int e = tid; e < (TCONV+2)*DDIM; e += 128) {
    int tt = e >> 7, d = e & 127;
    int t = t0 + tt;
    Xs[tt][d] = (t < LDIM) ? X[(size_t)t*DDIM + d] : 0.f;
  }
  __syncthreads();
  const int f = tid;
  if (f < FDIM) {
    float y[TCONV];
    #pragma unroll
    for (int t = 0; t < TCONV; t++) y[t] = 0.f;
    for (int dq = 0; dq < DDIM/4; dq++) {
      float4 xq[TCONV+2];
      #pragma unroll
      for (int i = 0; i < TCONV+2; i++) xq[i] = *(const float4*)&Xs[i][dq*4];
      #pragma unroll
      for (int ks = 0; ks < 3; ks++) {
        float w0 = wv[(ks*DDIM + dq*4+0)*FDIM + f];
        float w1 = wv[(ks*DDIM + dq*4+1)*FDIM + f];
        float w2 = wv[(ks*DDIM + dq*4+2)*FDIM + f];
        float w3 = wv[(ks*DDIM + dq*4+3)*FDIM + f];
        #pragma unroll
        for (int t = 0; t < TCONV; t++)
          y[t] += xq[t+ks].x*w0 + xq[t+ks].y*w1 + xq[t+ks].z*w2 + xq[t+ks].w*w3;
      }
    }
    float bv = bias[f];
    float mx = 0.f;
    #pragma unroll
    for (int t = 0; t < TCONV; t++) {
      if (t0 + t < LDIM - 2) mx = fmaxf(mx, fmaxf(y[t] + bv, 0.f));
    }
    atomicMax((unsigned int*)&out[(size_t)b*(2*FDIM) + z*FDIM + f], __float_as_uint(mx));
  }
}

extern "C" void kernel_launch(void* const* d_in, const int* in_sizes, int n_in,
                              void* d_out, int out_size, void* d_ws, size_t ws_size,
                              hipStream_t stream) {
  const float* ctx   = (const float*)d_in[0];
  const float* mn    = (const float*)d_in[1];
  const float* wconv = (const float*)d_in[2];
  const float* bias  = (const float*)d_in[3];
  float* out = (float*)d_out;

  // pool accumulators must start at 0 (d_out is poisoned before every call)
  hipMemsetAsync(d_out, 0, sizeof(float)*(size_t)out_size, stream);

  // Per-batch workspace: W (L*L) + row/col stats (14*L) + attC/outC/outM (3*L*D)
  const size_t perBatchFloats = (size_t)LDIM*LDIM + 14*(size_t)LDIM + 3*(size_t)LDIM*DDIM;
  const size_t perBatchBytes = perBatchFloats * sizeof(float);
  int nbMax = (int)(ws_size / perBatchBytes);
  if (nbMax < 1) nbMax = 1;
  if (nbMax > BDIM) nbMax = BDIM;

  for (int b0 = 0; b0 < BDIM; b0 += nbMax) {
    const int nb = (BDIM - b0 < nbMax) ? (BDIM - b0) : nbMax;
    float* Wbuf = (float*)d_ws;
    float* rowW = Wbuf + (size_t)nb*LDIM*LDIM;
    int*   rowI = (int*)(rowW + (size_t)nb*LDIM*3);
    float* rowS = (float*)(rowI + (size_t)nb*LDIM*3);
    float* colW = rowS + (size_t)nb*LDIM;
    int*   colI = (int*)(colW + (size_t)nb*LDIM*3);
    float* colS = (float*)(colI + (size_t)nb*LDIM*3);
    float* attC = colS + (size_t)nb*LDIM;
    float* outC = attC + (size_t)nb*LDIM*DDIM;
    float* outM = outC + (size_t)nb*LDIM*DDIM;
    const float* ctxb = ctx + (size_t)b0*LDIM*DDIM;
    const float* mnb  = mn  + (size_t)b0*LDIM*DDIM;

    gemm_nt<<<dim3(LDIM/64, LDIM/64, nb), 256, 0, stream>>>(ctxb, mnb, Wbuf);
    row_stats<<<dim3(LDIM, nb), 256, 0, stream>>>(Wbuf, rowW, rowI, rowS);
    col_stats<<<dim3(LDIM/64, nb), 256, 0, stream>>>(Wbuf, colW, colI, colS);
    hipMemsetAsync(attC, 0, (size_t)nb*LDIM*DDIM*sizeof(float), stream);
    scatter_att<<<dim3(LDIM, nb), 128, 0, stream>>>(ctxb, rowW, rowI, attC);
    make_outputs<<<dim3(LDIM, nb), 128, 0, stream>>>(ctxb, mnb, attC, rowS, colW, colI, colS, outC, outM);
    conv_pool<<<dim3((LDIM - 2 + TCONV - 1)/TCONV, nb, 2), 128, 0, stream>>>(
        outC, outM, wconv, bias, out + (size_t)b0*2*FDIM);
  }
}